// Round 12
// baseline (1040.624 us; speedup 1.0000x reference)
//
#include <hip/hip_runtime.h>

// LSTM, B=512 x T=1024, H=100, input_size=1.
// R16 = R15 resubmitted verbatim (R15 died to the same infra "container
// failed twice" error as R8; R9's verbatim resubmit of R8 ran fine).
// Audit: uniform barriers, 74.3KB LDS < 160KB ceiling, h/x write-read
// index mapping verified bijective, parity chain verified.
//
// R15: MFMA reformulation. R5-R14 (VALU path) pinned at 1200-1450
// cyc/batch-step across every structure; allocator caps arch VGPRs at <=64
// and parks persistent weights in AGPR (per-use move tax on VALU). MFMA
// reads AGPRs NATIVELY -> the parking becomes free. MfmaUtil was 0.0 in all
// rounds: the matrix pipes are idle.
// Formulation: gates[400x16] = [W_hh | bias | W_ih | W_ih] @ [h; 1; xhi; xlo]
//   K = 128 (100 h + 1 bias + 2 x-cols + pad), N = 16 batches/block,
//   M = 4 gates x 112-pad + W_out row (out-projection = extra M-tile,
//   computes out[t-1] = Wout.h[t-1]+b_out during step t -> free pipelining).
// W split: f16 hi + f16 lo (2 MFMA per tile-pair, W error ~2^-22).
// h single-plane f16 (err ~5e-5/gate dot; est absmax 1-3e-4).
// Gate-aligned ownership: wave w owns units 16w..16w+15 for ALL 4 gates
// (tiles {i,f,g,o} of the same unit range) -> cell update fully in-register.
// h passes step-to-step as pre-packed f16 B-fragments in LDS:
// 2x ds_write_b64 per wave (write), 4x ds_read_b128 per wave (read),
// parity double-buffered -> ONE barrier per step.
// 32 blocks x 512 thr (8 waves): waves 0-6 compute (wave 6 top 12 units are
// zero-padded rows -> h=0, writes suppressed), wave 7 = out-row tile + x/bias
// B-row writer + out stores.

#define HID   100
#define TLEN  1024
#define NB    16
#define BLOCK 512
#define INSTR 1033   // in_s row stride (floats): 1033 mod 32 = 9 -> 16 lanes
                     // at stride 9 banks = all distinct (conflict-free)

typedef _Float16 half8 __attribute__((ext_vector_type(8)));
typedef float    f32x4 __attribute__((ext_vector_type(4)));

#define MFMA(A,B,C) __builtin_amdgcn_mfma_f32_16x16x32_f16((A),(B),(C),0,0,0)

static __device__ __forceinline__ unsigned packh(_Float16 a, _Float16 b) {
    return (unsigned)__builtin_bit_cast(unsigned short, a)
         | ((unsigned)__builtin_bit_cast(unsigned short, b) << 16);
}

__global__ __launch_bounds__(BLOCK, 2)   // 2 waves/EU min -> 256-VGPR budget
void lstm_mfma(
    const float* __restrict__ input,   // [B, T]
    const float* __restrict__ W_ih,    // [4H]
    const float* __restrict__ W_hh,    // [4H, H]
    const float* __restrict__ b_ih,    // [4H]
    const float* __restrict__ b_hh,    // [4H]
    const float* __restrict__ W_out,   // [H]
    const float* __restrict__ b_out,   // [1]
    float* __restrict__ out)           // [B, T]
{
    const int tid  = threadIdx.x;
    const int lane = tid & 63;
    const int w    = tid >> 6;        // wave 0..7
    const int b0   = blockIdx.x * NB;
    const int q    = lane >> 4;       // k-subgroup (A/B) / D row-quad
    const int mrow = lane & 15;       // A row within tile / B col n

    // B-fragment LDS: [parity][kt][lane][4 dwords of 2xf16], 8 KB.
    // B[k][n]: n = lane&15, k = 32*kt + 8*(lane>>4) + elem  (elem 2d,2d+1
    // in dword d, low half = even elem). Same k-formula used for A packing:
    // any within-tile k-permutation of the true HW layout cancels in A.B.
    __shared__ __align__(16) unsigned B_lds[2][4][64][4];
    __shared__ float in_s[NB * INSTR];                       // 66 KB

    // ---- one-time staging ----
    for (int i = tid; i < NB * TLEN; i += BLOCK) {
        const int n = i >> 10, t = i & 1023;
        in_s[n * INSTR + t] = input[(b0 + n) * TLEN + t];
    }
    for (int i = tid; i < 2 * 4 * 64 * 4; i += BLOCK)
        ((unsigned*)B_lds)[i] = 0u;   // unwritten k-slots must be 0, not NaN

    // ---- A fragments (persistent; AGPR-parking is fine, MFMA reads them) --
    // waves 0..6: g in {i,f,g,o}: A row = unit u = 16w + mrow of gate g.
    //   k<100 -> W_hh ; k=100 -> bias (b_ih+b_hh) ; k=101,102 -> W_ih ; else 0
    // wave 7: out tile: row 0 = W_out (k<100), b_out at k=100; rows 1-15 = 0.
    half8 Ahi[4][4], Alo[4][4];       // [gate][kt]
    if (w < 7) {
        const int u = 16 * w + mrow;
        #pragma unroll
        for (int g = 0; g < 4; ++g) {
            #pragma unroll
            for (int kt = 0; kt < 4; ++kt) {
                half8 hh, hl;
                #pragma unroll
                for (int j = 0; j < 8; ++j) {
                    const int k = 32 * kt + 8 * q + j;
                    float v = 0.f;
                    if (u < HID) {
                        const int row = HID * g + u;
                        if (k < HID)           v = W_hh[row * HID + k];
                        else if (k == HID)     v = b_ih[row] + b_hh[row];
                        else if (k <= HID + 2) v = W_ih[row];
                    }
                    const _Float16 vh = (_Float16)v;
                    hh[j] = vh;
                    hl[j] = (_Float16)(v - (float)vh);
                }
                Ahi[g][kt] = hh; Alo[g][kt] = hl;
            }
        }
    } else {
        #pragma unroll
        for (int kt = 0; kt < 4; ++kt) {
            half8 hh, hl;
            #pragma unroll
            for (int j = 0; j < 8; ++j) {
                const int k = 32 * kt + 8 * q + j;
                float v = 0.f;
                if (mrow == 0) {
                    if (k < HID)       v = W_out[k];
                    else if (k == HID) v = b_out[0];
                }
                const _Float16 vh = (_Float16)v;
                hh[j] = vh;
                hl[j] = (_Float16)(v - (float)vh);
            }
            Ahi[0][kt] = hh; Alo[0][kt] = hl;
            Ahi[1][kt] = hh; Alo[1][kt] = hl;   // keep arrays fully init'd
            Ahi[2][kt] = hh; Alo[2][kt] = hl;
            Ahi[3][kt] = hh; Alo[3][kt] = hl;
        }
    }

    float c0 = 0.f, c1 = 0.f, c2 = 0.f, c3 = 0.f;   // cell state (4/lane)

    __syncthreads();                  // in_s + B zero visible
    // prologue: x[0] + bias-one row into parity 0 (k=100:1.0, 101:xhi, 102:xlo)
    if (w == 7 && lane < NB) {
        const float xv = in_s[lane * INSTR];
        const _Float16 xh = (_Float16)xv;
        const _Float16 xl = (_Float16)(xv - (float)xh);
        uint2 dv; dv.x = packh((_Float16)1.f, xh); dv.y = packh(xl, (_Float16)0.f);
        *(uint2*)&B_lds[0][3][lane][2] = dv;
    }
    __syncthreads();

    #pragma unroll 1
    for (int t = 0; t < TLEN; ++t) {
        const int p = t & 1;
        // ---- B fragments (all waves; 4x ds_read_b128) ----
        const half8 bf0 = *(const half8*)&B_lds[p][0][lane][0];
        const half8 bf1 = *(const half8*)&B_lds[p][1][lane][0];
        const half8 bf2 = *(const half8*)&B_lds[p][2][lane][0];
        const half8 bf3 = *(const half8*)&B_lds[p][3][lane][0];

        if (w < 7) {
            // ---- GEMM: 4 gates x 4 kt x {hi,lo} = 32 MFMA, 4 indep chains
            f32x4 a0 = {0.f,0.f,0.f,0.f}, a1 = {0.f,0.f,0.f,0.f};
            f32x4 a2 = {0.f,0.f,0.f,0.f}, a3 = {0.f,0.f,0.f,0.f};
            #define QSTEP(KT, BF) \
                a0 = MFMA(Ahi[0][KT], BF, a0); a1 = MFMA(Ahi[1][KT], BF, a1); \
                a2 = MFMA(Ahi[2][KT], BF, a2); a3 = MFMA(Ahi[3][KT], BF, a3); \
                a0 = MFMA(Alo[0][KT], BF, a0); a1 = MFMA(Alo[1][KT], BF, a1); \
                a2 = MFMA(Alo[2][KT], BF, a2); a3 = MFMA(Alo[3][KT], BF, a3);
            QSTEP(0, bf0) QSTEP(1, bf1) QSTEP(2, bf2) QSTEP(3, bf3)
            #undef QSTEP

            // ---- cell update, fully in-register.
            // D layout (HW-verified): col = lane&15 = n, row = 4*q + r
            // -> this lane holds gates of units U..U+3, batch n.
            _Float16 hh[4];
            #define CELL(R, CR) { \
                const float ig = a0[R], fg = a1[R], gg = a2[R], og = a3[R]; \
                const float is = __builtin_amdgcn_rcpf(1.f + __expf(-ig));  \
                const float fs = __builtin_amdgcn_rcpf(1.f + __expf(-fg));  \
                const float os = __builtin_amdgcn_rcpf(1.f + __expf(-og));  \
                const float gt = 1.f - 2.f * __builtin_amdgcn_rcpf(__expf(2.f*gg) + 1.f); \
                CR = fmaf(fs, CR, is * gt); \
                const float th = 1.f - 2.f * __builtin_amdgcn_rcpf(__expf(2.f*CR) + 1.f); \
                hh[R] = (_Float16)(os * th); }
            CELL(0, c0) CELL(1, c1) CELL(2, c2) CELL(3, c3)
            #undef CELL

            // ---- write h as next-parity B-fragment rows (k = U..U+3).
            // Suppress wave 6's padded units 100..111 (q>0).
            if (w < 6 || q == 0) {
                const int U = 16 * w + 4 * q;
                uint2 dv;
                dv.x = packh(hh[0], hh[1]);
                dv.y = packh(hh[2], hh[3]);
                *(uint2*)&B_lds[p ^ 1][U >> 5][(((U >> 3) & 3) << 4) | mrow]
                               [(U >> 1) & 3] = dv;
            }
        } else {
            // ---- wave 7: out-row tile (8 MFMA) -> out[t-1]; x[t+1] B-row.
            f32x4 ao = {0.f,0.f,0.f,0.f};
            ao = MFMA(Ahi[0][0], bf0, ao); ao = MFMA(Alo[0][0], bf0, ao);
            ao = MFMA(Ahi[0][1], bf1, ao); ao = MFMA(Alo[0][1], bf1, ao);
            ao = MFMA(Ahi[0][2], bf2, ao); ao = MFMA(Alo[0][2], bf2, ao);
            ao = MFMA(Ahi[0][3], bf3, ao); ao = MFMA(Alo[0][3], bf3, ao);
            if (lane < NB) {
                if (t > 0) out[(b0 + lane) * TLEN + (t - 1)] = ao[0];
                if (t + 1 < TLEN) {
                    const float xv = in_s[lane * INSTR + (t + 1)];
                    const _Float16 xh = (_Float16)xv;
                    const _Float16 xl = (_Float16)(xv - (float)xh);
                    uint2 dv; dv.x = packh((_Float16)1.f, xh);
                    dv.y = packh(xl, (_Float16)0.f);
                    *(uint2*)&B_lds[p ^ 1][3][lane][2] = dv;
                }
            }
        }
        __syncthreads();   // the ONLY barrier per step
    }

    // ---- epilogue: out[.,T-1] = Wout.h[T-1] + b_out (h[1023] in parity 0;
    // its bias-one at k=100 persists from the t=1021 x-write).
    if (w == 7) {
        const half8 bf0 = *(const half8*)&B_lds[0][0][lane][0];
        const half8 bf1 = *(const half8*)&B_lds[0][1][lane][0];
        const half8 bf2 = *(const half8*)&B_lds[0][2][lane][0];
        const half8 bf3 = *(const half8*)&B_lds[0][3][lane][0];
        f32x4 ao = {0.f,0.f,0.f,0.f};
        ao = MFMA(Ahi[0][0], bf0, ao); ao = MFMA(Alo[0][0], bf0, ao);
        ao = MFMA(Ahi[0][1], bf1, ao); ao = MFMA(Alo[0][1], bf1, ao);
        ao = MFMA(Ahi[0][2], bf2, ao); ao = MFMA(Alo[0][2], bf2, ao);
        ao = MFMA(Ahi[0][3], bf3, ao); ao = MFMA(Alo[0][3], bf3, ao);
        if (lane < NB) out[(b0 + lane) * TLEN + (TLEN - 1)] = ao[0];
    }
}

extern "C" void kernel_launch(void* const* d_in, const int* in_sizes, int n_in,
                              void* d_out, int out_size, void* d_ws, size_t ws_size,
                              hipStream_t stream) {
    const float* input = (const float*)d_in[0];
    const float* W_ih  = (const float*)d_in[1];
    const float* W_hh  = (const float*)d_in[2];
    const float* b_ih  = (const float*)d_in[3];
    const float* b_hh  = (const float*)d_in[4];
    const float* W_out = (const float*)d_in[5];
    const float* b_out = (const float*)d_in[6];
    float* out = (float*)d_out;

    const int B = in_sizes[0] / TLEN;  // 512
    lstm_mfma<<<B / NB, BLOCK, 0, stream>>>(input, W_ih, W_hh, b_ih, b_hh,
                                            W_out, b_out, out);
}